// Round 2
// baseline (153.185 us; speedup 1.0000x reference)
//
#include <hip/hip_runtime.h>

#define NBLK 2048
#define NTHR 256

__global__ __launch_bounds__(NTHR) void huber_fused(
    const float* __restrict__ x, const float* __restrict__ y,
    float* __restrict__ out, float* __restrict__ partial,
    unsigned* __restrict__ counter, long long n, float inv_n)
{
    const long long n4 = n >> 2;                 // float4 count
    const float4* __restrict__ x4 = (const float4*)x;
    const float4* __restrict__ y4 = (const float4*)y;

    long long tid = (long long)blockIdx.x * blockDim.x + threadIdx.x;
    long long stride = (long long)gridDim.x * blockDim.x;

    float acc = 0.0f;
    for (long long i = tid; i < n4; i += stride) {
        float4 a = x4[i];
        float4 b = y4[i];
        float d0 = a.x - b.x, d1 = a.y - b.y, d2 = a.z - b.z, d3 = a.w - b.w;
        float a0 = fabsf(d0), a1 = fabsf(d1), a2 = fabsf(d2), a3 = fabsf(d3);
        acc += (a0 <= 1.0f) ? 0.5f * d0 * d0 : a0;
        acc += (a1 <= 1.0f) ? 0.5f * d1 * d1 : a1;
        acc += (a2 <= 1.0f) ? 0.5f * d2 * d2 : a2;
        acc += (a3 <= 1.0f) ? 0.5f * d3 * d3 : a3;
    }

    // scalar tail (n not divisible by 4)
    if (tid == 0) {
        for (long long i = n4 << 2; i < n; ++i) {
            float d = x[i] - y[i];
            float ad = fabsf(d);
            acc += (ad <= 1.0f) ? 0.5f * d * d : ad;
        }
    }

    // wave64 reduction
    #pragma unroll
    for (int off = 32; off > 0; off >>= 1)
        acc += __shfl_down(acc, off, 64);

    __shared__ float smem[NTHR / 64];
    __shared__ int is_last;
    int lane = threadIdx.x & 63;
    int wv   = threadIdx.x >> 6;
    if (lane == 0) smem[wv] = acc;
    __syncthreads();
    if (threadIdx.x == 0) {
        float t = 0.0f;
        #pragma unroll
        for (int i = 0; i < NTHR / 64; ++i) t += smem[i];
        // device-scope store so the last block (possibly another XCD) sees it
        __hip_atomic_store(&partial[blockIdx.x], t, __ATOMIC_RELEASE,
                           __HIP_MEMORY_SCOPE_AGENT);
        unsigned prev = __hip_atomic_fetch_add(counter, 1u, __ATOMIC_ACQ_REL,
                                               __HIP_MEMORY_SCOPE_AGENT);
        is_last = (prev == (unsigned)(gridDim.x - 1));
    }
    __syncthreads();

    if (is_last) {
        // last block reduces all partials in fixed order -> deterministic
        float a2s = 0.0f;
        for (int i = threadIdx.x; i < NBLK; i += NTHR)
            a2s += __hip_atomic_load(&partial[i], __ATOMIC_RELAXED,
                                     __HIP_MEMORY_SCOPE_AGENT);
        #pragma unroll
        for (int off = 32; off > 0; off >>= 1)
            a2s += __shfl_down(a2s, off, 64);
        __syncthreads();   // reuse smem safely
        if (lane == 0) smem[wv] = a2s;
        __syncthreads();
        if (threadIdx.x == 0) {
            float t = 0.0f;
            #pragma unroll
            for (int i = 0; i < NTHR / 64; ++i) t += smem[i];
            out[0] = t * inv_n;
        }
    }
}

extern "C" void kernel_launch(void* const* d_in, const int* in_sizes, int n_in,
                              void* d_out, int out_size, void* d_ws, size_t ws_size,
                              hipStream_t stream)
{
    const float* x = (const float*)d_in[0];
    const float* y = (const float*)d_in[1];
    float* out = (float*)d_out;
    float* partial = (float*)d_ws;                       // NBLK floats
    unsigned* counter = (unsigned*)((char*)d_ws + NBLK * sizeof(float));

    long long n = (long long)in_sizes[0];

    hipMemsetAsync(counter, 0, sizeof(unsigned), stream);  // clears 0xAA poison
    huber_fused<<<NBLK, NTHR, 0, stream>>>(x, y, out, partial, counter, n,
                                           (float)(1.0 / (double)n));
}

// Round 3
// 67.279 us; speedup vs baseline: 2.2769x; 2.2769x over previous
//
#include <hip/hip_runtime.h>

#define NBLK 2048
#define NTHR 256

__global__ __launch_bounds__(NTHR) void huber_fused(
    const float* __restrict__ x, const float* __restrict__ y,
    float* __restrict__ out, float* __restrict__ partial,
    unsigned* __restrict__ counter, long long n, float inv_n)
{
    const long long n4 = n >> 2;                 // float4 count
    const float4* __restrict__ x4 = (const float4*)x;
    const float4* __restrict__ y4 = (const float4*)y;

    long long tid = (long long)blockIdx.x * blockDim.x + threadIdx.x;
    long long stride = (long long)gridDim.x * blockDim.x;

    float acc = 0.0f;
    for (long long i = tid; i < n4; i += stride) {
        float4 a = x4[i];
        float4 b = y4[i];
        float d0 = a.x - b.x, d1 = a.y - b.y, d2 = a.z - b.z, d3 = a.w - b.w;
        float a0 = fabsf(d0), a1 = fabsf(d1), a2 = fabsf(d2), a3 = fabsf(d3);
        acc += (a0 <= 1.0f) ? 0.5f * d0 * d0 : a0;
        acc += (a1 <= 1.0f) ? 0.5f * d1 * d1 : a1;
        acc += (a2 <= 1.0f) ? 0.5f * d2 * d2 : a2;
        acc += (a3 <= 1.0f) ? 0.5f * d3 * d3 : a3;
    }

    // scalar tail (n not divisible by 4)
    if (tid == 0) {
        for (long long i = n4 << 2; i < n; ++i) {
            float d = x[i] - y[i];
            float ad = fabsf(d);
            acc += (ad <= 1.0f) ? 0.5f * d * d : ad;
        }
    }

    // wave64 reduction
    #pragma unroll
    for (int off = 32; off > 0; off >>= 1)
        acc += __shfl_down(acc, off, 64);

    __shared__ float smem[NTHR / 64];
    __shared__ int is_last;
    int lane = threadIdx.x & 63;
    int wv   = threadIdx.x >> 6;
    if (lane == 0) smem[wv] = acc;
    __syncthreads();
    if (threadIdx.x == 0) {
        float t = 0.0f;
        #pragma unroll
        for (int i = 0; i < NTHR / 64; ++i) t += smem[i];
        // RELAXED agent store: write-through to coherence point, NO buffer_wbl2.
        __hip_atomic_store(&partial[blockIdx.x], t, __ATOMIC_RELAXED,
                           __HIP_MEMORY_SCOPE_AGENT);
        // Ordering half of a release fence, without the cache-writeback half:
        // the sc-flagged store has retired to the coherence point once vmcnt==0.
        asm volatile("s_waitcnt vmcnt(0)" ::: "memory");
        unsigned prev = __hip_atomic_fetch_add(counter, 1u, __ATOMIC_RELAXED,
                                               __HIP_MEMORY_SCOPE_AGENT);
        is_last = (prev == (unsigned)(NBLK - 1));
    }
    __syncthreads();

    if (is_last) {
        // single acquire fence, executed by ONE block only (one buffer_inv total)
        __builtin_amdgcn_fence(__ATOMIC_ACQUIRE, "agent");
        float a2s = 0.0f;
        for (int i = threadIdx.x; i < NBLK; i += NTHR)
            a2s += __hip_atomic_load(&partial[i], __ATOMIC_RELAXED,
                                     __HIP_MEMORY_SCOPE_AGENT);
        #pragma unroll
        for (int off = 32; off > 0; off >>= 1)
            a2s += __shfl_down(a2s, off, 64);
        __syncthreads();   // smem reuse
        if (lane == 0) smem[wv] = a2s;
        __syncthreads();
        if (threadIdx.x == 0) {
            float t = 0.0f;
            #pragma unroll
            for (int i = 0; i < NTHR / 64; ++i) t += smem[i];
            out[0] = t * inv_n;
        }
    }
}

extern "C" void kernel_launch(void* const* d_in, const int* in_sizes, int n_in,
                              void* d_out, int out_size, void* d_ws, size_t ws_size,
                              hipStream_t stream)
{
    const float* x = (const float*)d_in[0];
    const float* y = (const float*)d_in[1];
    float* out = (float*)d_out;
    float* partial = (float*)d_ws;                          // NBLK floats
    unsigned* counter = (unsigned*)((char*)d_ws + 8192);    // own cache line

    long long n = (long long)in_sizes[0];

    hipMemsetAsync(counter, 0, sizeof(unsigned), stream);   // clears 0xAA poison
    huber_fused<<<NBLK, NTHR, 0, stream>>>(x, y, out, partial, counter, n,
                                           (float)(1.0 / (double)n));
}

// Round 4
// 64.699 us; speedup vs baseline: 2.3676x; 1.0399x over previous
//
#include <hip/hip_runtime.h>

#define NBLK 2048
#define NTHR 256

__global__ __launch_bounds__(NTHR) void huber_fused(
    const float* __restrict__ x, const float* __restrict__ y,
    float* __restrict__ out, long long n, float inv_n)
{
    const long long n4 = n >> 2;                 // float4 count
    const float4* __restrict__ x4 = (const float4*)x;
    const float4* __restrict__ y4 = (const float4*)y;

    long long tid = (long long)blockIdx.x * blockDim.x + threadIdx.x;
    long long stride = (long long)gridDim.x * blockDim.x;

    float acc = 0.0f;
    for (long long i = tid; i < n4; i += stride) {
        float4 a = x4[i];
        float4 b = y4[i];
        float d0 = a.x - b.x, d1 = a.y - b.y, d2 = a.z - b.z, d3 = a.w - b.w;
        float a0 = fabsf(d0), a1 = fabsf(d1), a2 = fabsf(d2), a3 = fabsf(d3);
        acc += (a0 <= 1.0f) ? 0.5f * d0 * d0 : a0;
        acc += (a1 <= 1.0f) ? 0.5f * d1 * d1 : a1;
        acc += (a2 <= 1.0f) ? 0.5f * d2 * d2 : a2;
        acc += (a3 <= 1.0f) ? 0.5f * d3 * d3 : a3;
    }

    // scalar tail (n not divisible by 4)
    if (tid == 0) {
        for (long long i = n4 << 2; i < n; ++i) {
            float d = x[i] - y[i];
            float ad = fabsf(d);
            acc += (ad <= 1.0f) ? 0.5f * d * d : ad;
        }
    }

    // wave64 reduction
    #pragma unroll
    for (int off = 32; off > 0; off >>= 1)
        acc += __shfl_down(acc, off, 64);

    __shared__ float smem[NTHR / 64];
    int lane = threadIdx.x & 63;
    int wv   = threadIdx.x >> 6;
    if (lane == 0) smem[wv] = acc;
    __syncthreads();
    if (threadIdx.x == 0) {
        float t = 0.0f;
        #pragma unroll
        for (int i = 0; i < NTHR / 64; ++i) t += smem[i];
        // fire-and-forget device-scope FP atomic: executes at the coherence
        // point, no cache maintenance, no ordering stall. 2048 total adds.
        atomicAdd(out, t * inv_n);
    }
}

extern "C" void kernel_launch(void* const* d_in, const int* in_sizes, int n_in,
                              void* d_out, int out_size, void* d_ws, size_t ws_size,
                              hipStream_t stream)
{
    const float* x = (const float*)d_in[0];
    const float* y = (const float*)d_in[1];
    float* out = (float*)d_out;

    long long n = (long long)in_sizes[0];

    hipMemsetAsync(out, 0, sizeof(float), stream);  // zero accumulator each call
    huber_fused<<<NBLK, NTHR, 0, stream>>>(x, y, out, n,
                                           (float)(1.0 / (double)n));
}

// Round 5
// 47.133 us; speedup vs baseline: 3.2500x; 1.3727x over previous
//
#include <hip/hip_runtime.h>

#define NBLK 2048
#define NTHR 256

__global__ __launch_bounds__(NTHR) void huber_partial(
    const float* __restrict__ x, const float* __restrict__ y,
    float* __restrict__ partial, long long n)
{
    const long long n4 = n >> 2;                 // float4 count
    const float4* __restrict__ x4 = (const float4*)x;
    const float4* __restrict__ y4 = (const float4*)y;

    long long tid = (long long)blockIdx.x * blockDim.x + threadIdx.x;
    long long stride = (long long)gridDim.x * blockDim.x;

    float acc = 0.0f;
    for (long long i = tid; i < n4; i += stride) {
        float4 a = x4[i];
        float4 b = y4[i];
        float d0 = a.x - b.x, d1 = a.y - b.y, d2 = a.z - b.z, d3 = a.w - b.w;
        float a0 = fabsf(d0), a1 = fabsf(d1), a2 = fabsf(d2), a3 = fabsf(d3);
        acc += (a0 <= 1.0f) ? 0.5f * d0 * d0 : a0;
        acc += (a1 <= 1.0f) ? 0.5f * d1 * d1 : a1;
        acc += (a2 <= 1.0f) ? 0.5f * d2 * d2 : a2;
        acc += (a3 <= 1.0f) ? 0.5f * d3 * d3 : a3;
    }

    // scalar tail (n not divisible by 4)
    if (tid == 0) {
        for (long long i = n4 << 2; i < n; ++i) {
            float d = x[i] - y[i];
            float ad = fabsf(d);
            acc += (ad <= 1.0f) ? 0.5f * d * d : ad;
        }
    }

    // wave64 reduction
    #pragma unroll
    for (int off = 32; off > 0; off >>= 1)
        acc += __shfl_down(acc, off, 64);

    __shared__ float smem[NTHR / 64];
    int lane = threadIdx.x & 63;
    int wv   = threadIdx.x >> 6;
    if (lane == 0) smem[wv] = acc;
    __syncthreads();
    if (threadIdx.x == 0) {
        float t = 0.0f;
        #pragma unroll
        for (int i = 0; i < NTHR / 64; ++i) t += smem[i];
        partial[blockIdx.x] = t;
    }
}

__global__ __launch_bounds__(NTHR) void huber_final(
    const float* __restrict__ partial, float* __restrict__ out, float inv_n)
{
    // NBLK floats = NBLK/4 float4; 256 threads read 2 float4 each.
    const float4* __restrict__ p4 = (const float4*)partial;
    float acc = 0.0f;
    #pragma unroll
    for (int r = 0; r < NBLK / 4 / NTHR; ++r) {
        float4 v = p4[r * NTHR + threadIdx.x];
        acc += (v.x + v.y) + (v.z + v.w);
    }

    #pragma unroll
    for (int off = 32; off > 0; off >>= 1)
        acc += __shfl_down(acc, off, 64);

    __shared__ float smem[NTHR / 64];
    int lane = threadIdx.x & 63;
    int wv   = threadIdx.x >> 6;
    if (lane == 0) smem[wv] = acc;
    __syncthreads();
    if (threadIdx.x == 0) {
        float t = 0.0f;
        #pragma unroll
        for (int i = 0; i < NTHR / 64; ++i) t += smem[i];
        out[0] = t * inv_n;
    }
}

extern "C" void kernel_launch(void* const* d_in, const int* in_sizes, int n_in,
                              void* d_out, int out_size, void* d_ws, size_t ws_size,
                              hipStream_t stream)
{
    const float* x = (const float*)d_in[0];
    const float* y = (const float*)d_in[1];
    float* out = (float*)d_out;
    float* partial = (float*)d_ws;          // NBLK floats of scratch

    long long n = (long long)in_sizes[0];

    huber_partial<<<NBLK, NTHR, 0, stream>>>(x, y, partial, n);
    huber_final<<<1, NTHR, 0, stream>>>(partial, out, (float)(1.0 / (double)n));
}